// Round 3
// baseline (1895.864 us; speedup 1.0000x reference)
//
#include <hip/hip_runtime.h>
#include <hip/hip_bf16.h>

typedef unsigned short u16;
typedef unsigned int u32;

#define L_SEQ 4096
#define N_TOK 16384
#define D_MODEL 1024
#define R_DIM 16
#define PLU 120
#define G_DIM 256
#define TM 16

__device__ __forceinline__ float bf2f(u16 u) {
  return __uint_as_float(((u32)u) << 16);
}

__device__ __forceinline__ u16 f2bf(float f) {
  u32 x = __float_as_uint(f);
  u32 lsb = (x >> 16) & 1u;
  x += 0x7fffu + lsb;
  return (u16)(x >> 16);
}

// pair (i,j) for plucker index k, matching np.triu_indices(16, k=1) order
__device__ __forceinline__ void pair_from_k(int k, int& pi, int& pj) {
  int i = 0, kk = k, span = R_DIM - 1;
  while (kk >= span) { kk -= span; --span; ++i; }
  pi = i;
  pj = i + 1 + kk;
}

// -------- K0: dtype probe. flag=1 if h is bf16, 0 if fp32 ------------------
// For bf16 data the LOW u16 of each 32-bit word is a valid bf16 value with
// exponent in ~[100,140] (N(0,1) data). For fp32 data the low u16 is uniform
// mantissa bits -> ~16% hit rate. 256 samples, threshold 128: >15 sigma.
__global__ __launch_bounds__(256) void k_probe(const u32* __restrict__ hw,
                                               int* __restrict__ flag) {
  __shared__ int cnt;
  if (threadIdx.x == 0) cnt = 0;
  __syncthreads();
  const u32 w = hw[threadIdx.x];
  const u32 e = (w >> 7) & 0xFFu;
  if (e >= 100u && e <= 140u) atomicAdd(&cnt, 1);
  __syncthreads();
  if (threadIdx.x == 0) *flag = (cnt >= 128) ? 1 : 0;
}

// -------- K0b: normalize a tensor to bf16 (copy if bf16, round if fp32) ----
__global__ __launch_bounds__(256) void k_cvt(const void* __restrict__ src,
                                             u16* __restrict__ dst, int n,
                                             const int* __restrict__ flagp) {
  const int i = blockIdx.x * 256 + threadIdx.x;
  if (i >= n) return;
  if (*flagp)
    dst[i] = ((const u16*)src)[i];
  else
    dst[i] = f2bf(((const float*)src)[i]);
}

// ---------------- K1: z = h @ red_w + red_b  (N x 16, fp32) ----------------
__global__ __launch_bounds__(256) void k_reduce(const void* __restrict__ hv,
                                                const u16* __restrict__ red_w,
                                                const u16* __restrict__ red_b,
                                                float* __restrict__ z,
                                                const int* __restrict__ flagp) {
  __shared__ alignas(16) u16 hs[TM * D_MODEL];  // 32 KB (bf16-normalized h)
  const int tid = threadIdx.x;
  const int t0 = blockIdx.x * TM;
  const int isbf = *flagp;

  if (isbf) {
    const uint4* src = (const uint4*)((const u16*)hv + (size_t)t0 * D_MODEL);
    uint4* dst = (uint4*)hs;
#pragma unroll
    for (int it = 0; it < (TM * D_MODEL / 8) / 256; ++it)
      dst[tid + it * 256] = src[tid + it * 256];
  } else {
    const float4* src = (const float4*)((const float*)hv + (size_t)t0 * D_MODEL);
    u32* dst = (u32*)hs;
#pragma unroll
    for (int it = 0; it < (TM * D_MODEL / 4) / 256; ++it) {
      const int idx = tid + it * 256;
      const float4 v = src[idx];
      dst[idx * 2 + 0] = (u32)f2bf(v.x) | ((u32)f2bf(v.y) << 16);
      dst[idx * 2 + 1] = (u32)f2bf(v.z) | ((u32)f2bf(v.w) << 16);
    }
  }
  __syncthreads();

  const int m = tid >> 4, c = tid & 15;
  const u16* hrow = hs + m * D_MODEL;
  float acc = 0.f;
#pragma unroll 8
  for (int i = 0; i < D_MODEL; i += 2) {
    u32 hv2 = *(const u32*)(hrow + i);
    float h0 = __uint_as_float(hv2 << 16);
    float h1 = __uint_as_float(hv2 & 0xffff0000u);
    acc = fmaf(h0, bf2f(red_w[i * R_DIM + c]), acc);
    acc = fmaf(h1, bf2f(red_w[(i + 1) * R_DIM + c]), acc);
  }
  z[(size_t)(t0 + m) * R_DIM + c] = acc + bf2f(red_b[c]);
}

// ------- K2: fused plucker -> GEMM1 -> gelu -> GEMM2, summed over deltas ----
__global__ __launch_bounds__(256) void k_geom(const float* __restrict__ z,
                                              const u16* __restrict__ g1w,
                                              const u16* __restrict__ g1b,
                                              const u16* __restrict__ g2w,
                                              const u16* __restrict__ g2b,
                                              u16* __restrict__ g) {
  __shared__ alignas(16) float zs[TM][17];
  __shared__ alignas(16) float zp[TM][17];
  __shared__ alignas(16) float Ps[PLU][20];    // k-major, stride 20 floats
  __shared__ alignas(16) float As[G_DIM][20];  // k-major
  __shared__ alignas(16) float nrm_part[TM][8];
  __shared__ alignas(16) float rnorm_s[TM];

  const int tid = threadIdx.x;
  const int t0 = blockIdx.x * TM;
  const int l0 = t0 & (L_SEQ - 1);

  {
    const int m = tid >> 4, c = tid & 15;
    zs[m][c] = z[(size_t)(t0 + m) * R_DIM + c];
  }

  float acc[TM * 4];
#pragma unroll
  for (int q = 0; q < TM * 4; ++q) acc[q] = 0.f;

  const int deltas[6] = {1, 2, 4, 8, 16, 32};
#pragma unroll 1
  for (int dd = 0; dd < 6; ++dd) {
    const int delta = deltas[dd];
    __syncthreads();  // all threads done with previous As/Ps (and zs at dd=0)
    {
      const int m = tid >> 4, c = tid & 15;
      const int l = l0 + m;
      zp[m][c] = (l >= delta) ? z[(size_t)(t0 + m - delta) * R_DIM + c] : 0.f;
    }
    __syncthreads();
    // plucker -> Ps (unnormalized; normalization folded into GEMM1)
    for (int idx = tid; idx < PLU * TM; idx += 256) {
      const int k = idx >> 4, m = idx & 15;
      int pi, pj;
      pair_from_k(k, pi, pj);
      Ps[k][m] = zp[m][pi] * zs[m][pj] - zp[m][pj] * zs[m][pi];
    }
    __syncthreads();
    // norms
    if (tid < TM * 8) {
      const int m = tid >> 3, pp = tid & 7;
      float s = 0.f;
      for (int k = pp; k < PLU; k += 8) {
        float v = Ps[k][m];
        s = fmaf(v, v, s);
      }
      nrm_part[m][pp] = s;
    }
    __syncthreads();
    if (tid < TM) {
      float s = 0.f;
#pragma unroll
      for (int pp = 0; pp < 8; ++pp) s += nrm_part[tid][pp];
      rnorm_s[tid] = 1.0f / fmaxf(sqrtf(s), 1e-6f);
    }
    __syncthreads();
    // GEMM1 (this thread owns col=tid of d_geom) + gelu -> As
    {
      float a1[TM];
#pragma unroll
      for (int m = 0; m < TM; ++m) a1[m] = 0.f;
      for (int k = 0; k < PLU; ++k) {
        const float w = bf2f(g1w[k * G_DIM + tid]);
        const float4 p0 = *(const float4*)&Ps[k][0];
        const float4 p1 = *(const float4*)&Ps[k][4];
        const float4 p2 = *(const float4*)&Ps[k][8];
        const float4 p3 = *(const float4*)&Ps[k][12];
        const float pv[16] = {p0.x, p0.y, p0.z, p0.w, p1.x, p1.y, p1.z, p1.w,
                              p2.x, p2.y, p2.z, p2.w, p3.x, p3.y, p3.z, p3.w};
#pragma unroll
        for (int m = 0; m < TM; ++m) a1[m] = fmaf(pv[m], w, a1[m]);
      }
      const float b1 = bf2f(g1b[tid]);
#pragma unroll
      for (int m = 0; m < TM; ++m) {
        const float x = a1[m] * rnorm_s[m] + b1;
        const float ge = 0.5f * x * (1.0f + erff(x * 0.70710678118654752f));
        // zero masked tokens so their GEMM2 contribution vanishes
        As[tid][m] = (l0 + m >= delta) ? ge : 0.f;
      }
    }
    __syncthreads();
    // GEMM2: accumulate into per-thread geom registers (cols tid + j*256)
    for (int k = 0; k < G_DIM; ++k) {
      const float w0 = bf2f(g2w[k * D_MODEL + tid]);
      const float w1 = bf2f(g2w[k * D_MODEL + tid + 256]);
      const float w2 = bf2f(g2w[k * D_MODEL + tid + 512]);
      const float w3 = bf2f(g2w[k * D_MODEL + tid + 768]);
      const float4 a0 = *(const float4*)&As[k][0];
      const float4 a1v = *(const float4*)&As[k][4];
      const float4 a2 = *(const float4*)&As[k][8];
      const float4 a3 = *(const float4*)&As[k][12];
      const float av[16] = {a0.x,  a0.y,  a0.z,  a0.w,  a1v.x, a1v.y,
                            a1v.z, a1v.w, a2.x,  a2.y,  a2.z,  a2.w,
                            a3.x,  a3.y,  a3.z,  a3.w};
      const float wj[4] = {w0, w1, w2, w3};
#pragma unroll
      for (int m = 0; m < TM; ++m)
#pragma unroll
        for (int j = 0; j < 4; ++j)
          acc[m * 4 + j] = fmaf(av[m], wj[j], acc[m * 4 + j]);
    }
  }

  // finalize: g = (sum_delta dot + count*b2) / max(count,1), store bf16
  const float b2v[4] = {bf2f(g2b[tid]), bf2f(g2b[tid + 256]),
                        bf2f(g2b[tid + 512]), bf2f(g2b[tid + 768])};
#pragma unroll
  for (int m = 0; m < TM; ++m) {
    const int l = l0 + m;
    const float cntf = (float)((l >= 1) + (l >= 2) + (l >= 4) + (l >= 8) +
                               (l >= 16) + (l >= 32));
    const float inv = 1.0f / fmaxf(cntf, 1.0f);
    u16* grow = g + (size_t)(t0 + m) * D_MODEL;
#pragma unroll
    for (int j = 0; j < 4; ++j)
      grow[tid + j * 256] = f2bf((acc[m * 4 + j] + cntf * b2v[j]) * inv);
  }
}

// -------- K3: alpha = sigmoid([h,g] @ gate_w + gate_b); blend --------------
__global__ __launch_bounds__(256) void k_gate(const void* __restrict__ hv,
                                              const u16* __restrict__ g,
                                              const u16* __restrict__ gw,
                                              const u16* __restrict__ gb,
                                              void* __restrict__ outv,
                                              const int* __restrict__ flagp) {
  __shared__ alignas(16) float xs[128][TM + 4];  // k-major chunk, stride 20
  const int tid = threadIdx.x;
  const int t0 = blockIdx.x * TM;
  const int m16 = tid >> 4, c16 = tid & 15;
  const int isbf = *flagp;

  float acc[TM * 4];
#pragma unroll
  for (int q = 0; q < TM * 4; ++q) acc[q] = 0.f;

#pragma unroll 1
  for (int chunk = 0; chunk < 16; ++chunk) {
    __syncthreads();
    {
      const int koff = (chunk & 7) * 128;
      if (chunk < 8 && !isbf) {
        // h is fp32
        const float* src =
            (const float*)hv + (size_t)(t0 + m16) * D_MODEL + koff + c16 * 8;
        const float4 a = *(const float4*)src;
        const float4 b = *(const float4*)(src + 4);
        xs[c16 * 8 + 0][m16] = a.x;
        xs[c16 * 8 + 1][m16] = a.y;
        xs[c16 * 8 + 2][m16] = a.z;
        xs[c16 * 8 + 3][m16] = a.w;
        xs[c16 * 8 + 4][m16] = b.x;
        xs[c16 * 8 + 5][m16] = b.y;
        xs[c16 * 8 + 6][m16] = b.z;
        xs[c16 * 8 + 7][m16] = b.w;
      } else {
        // bf16 source (h when isbf, or g from ws which is always bf16)
        const u16* base = (chunk < 8) ? (const u16*)hv : g;
        const u16* src = base + (size_t)(t0 + m16) * D_MODEL + koff + c16 * 8;
        uint4 v = *(const uint4*)src;
        const u32 vv[4] = {v.x, v.y, v.z, v.w};
#pragma unroll
        for (int u = 0; u < 4; ++u) {
          xs[c16 * 8 + 2 * u][m16] = __uint_as_float(vv[u] << 16);
          xs[c16 * 8 + 2 * u + 1][m16] = __uint_as_float(vv[u] & 0xffff0000u);
        }
      }
    }
    __syncthreads();
    const u16* wbase = gw + (size_t)chunk * 128 * D_MODEL + tid;
    for (int k = 0; k < 128; ++k) {
      const float w0 = bf2f(wbase[k * D_MODEL]);
      const float w1 = bf2f(wbase[k * D_MODEL + 256]);
      const float w2 = bf2f(wbase[k * D_MODEL + 512]);
      const float w3 = bf2f(wbase[k * D_MODEL + 768]);
      const float4 a0 = *(const float4*)&xs[k][0];
      const float4 a1v = *(const float4*)&xs[k][4];
      const float4 a2 = *(const float4*)&xs[k][8];
      const float4 a3 = *(const float4*)&xs[k][12];
      const float av[16] = {a0.x,  a0.y,  a0.z,  a0.w,  a1v.x, a1v.y,
                            a1v.z, a1v.w, a2.x,  a2.y,  a2.z,  a2.w,
                            a3.x,  a3.y,  a3.z,  a3.w};
      const float wj[4] = {w0, w1, w2, w3};
#pragma unroll
      for (int m = 0; m < TM; ++m)
#pragma unroll
        for (int j = 0; j < 4; ++j)
          acc[m * 4 + j] = fmaf(av[m], wj[j], acc[m * 4 + j]);
    }
  }

  const float bj[4] = {bf2f(gb[tid]), bf2f(gb[tid + 256]), bf2f(gb[tid + 512]),
                       bf2f(gb[tid + 768])};
#pragma unroll
  for (int m = 0; m < TM; ++m) {
    const size_t row = (size_t)(t0 + m) * D_MODEL;
#pragma unroll
    for (int j = 0; j < 4; ++j) {
      const int c = tid + j * 256;
      const float xv = acc[m * 4 + j] + bj[j];
      const float al = 1.0f / (1.0f + expf(-xv));
      const float hval =
          isbf ? bf2f(((const u16*)hv)[row + c]) : ((const float*)hv)[row + c];
      const float gval = bf2f(g[row + c]);
      const float o = fmaf(al, hval - gval, gval);
      if (isbf)
        ((u16*)outv)[row + c] = f2bf(o);
      else
        ((float*)outv)[row + c] = o;
    }
  }
}

// ---------------------------- launch ---------------------------------------
// ws layout (bytes):
//   [0,256)                      : int flag
//   [256, 256+1MB)               : z fp32 (N_TOK x 16)
//   [+, +32MB)                   : g bf16 (N_TOK x 1024)
//   [+, +~4.6MB)                 : converted bf16 weights/biases
#define WS_OFF_Z 256
#define WS_OFF_G (256 + 1048576)
#define WS_OFF_W (256 + 1048576 + 33554432)

#define W_REDW 0
#define W_REDB 16384
#define W_G1W 16400
#define W_G1B 47120
#define W_G2W 47376
#define W_G2B 309520
#define W_GW 310544
#define W_GB 2407696

extern "C" void kernel_launch(void* const* d_in, const int* in_sizes, int n_in,
                              void* d_out, int out_size, void* d_ws,
                              size_t ws_size, hipStream_t stream) {
  const void* h = d_in[0];
  int* flag = (int*)d_ws;
  float* z = (float*)((char*)d_ws + WS_OFF_Z);
  u16* g = (u16*)((char*)d_ws + WS_OFF_G);
  u16* wbuf = (u16*)((char*)d_ws + WS_OFF_W);

  k_probe<<<1, 256, 0, stream>>>((const u32*)h, flag);

  const int woff[8] = {W_REDW, W_REDB, W_G1W, W_G1B, W_G2W, W_G2B, W_GW, W_GB};
  for (int i = 0; i < 8; ++i) {
    const int n = in_sizes[i + 1];
    k_cvt<<<(n + 255) / 256, 256, 0, stream>>>(d_in[i + 1], wbuf + woff[i], n,
                                               flag);
  }

  dim3 grid(N_TOK / TM);
  k_reduce<<<grid, 256, 0, stream>>>(h, wbuf + W_REDW, wbuf + W_REDB, z, flag);
  k_geom<<<grid, 256, 0, stream>>>(z, wbuf + W_G1W, wbuf + W_G1B, wbuf + W_G2W,
                                   wbuf + W_G2B, g);
  k_gate<<<grid, 256, 0, stream>>>(h, g, wbuf + W_GW, wbuf + W_GB, d_out, flag);
}

// Round 4
// 567.206 us; speedup vs baseline: 3.3425x; 3.3425x over previous
//
#include <hip/hip_runtime.h>
#include <hip/hip_bf16.h>
#include <math.h>

typedef unsigned short u16;
typedef unsigned int u32;
typedef __attribute__((ext_vector_type(8))) short short8;
typedef __attribute__((ext_vector_type(4))) float f32x4;

#define L_SEQ 4096
#define N_TOK 16384
#define D_MODEL 1024
#define R_DIM 16
#define PLU 120
#define G_DIM 256
#define K_CAT 1536   // 6 deltas * 256
#define K_GATE 2048

__device__ __forceinline__ u16 f2bf(float f) {
  u32 x = __float_as_uint(f);
  u32 lsb = (x >> 16) & 1u;
  x += 0x7fffu + lsb;
  return (u16)(x >> 16);
}
__device__ __forceinline__ float bf2f(u16 u) {
  return __uint_as_float(((u32)u) << 16);
}
__device__ __forceinline__ u32 pack2(float a, float b) {
  return (u32)f2bf(a) | ((u32)f2bf(b) << 16);
}

// pair (i,j) for plucker index k, matching np.triu_indices(16, k=1)
__device__ __forceinline__ void pair_from_k(int k, int& pi, int& pj) {
  int i = 0, kk = k, span = R_DIM - 1;
  while (kk >= span) { kk -= span; --span; ++i; }
  pi = i;
  pj = i + 1 + kk;
}

// ------------- K_cvtT: fp32 [K x N] -> bf16 [N x K] (transpose) -------------
__global__ __launch_bounds__(256) void k_cvtT(const float* __restrict__ src,
                                              u16* __restrict__ dst, int K,
                                              int N) {
  __shared__ float t[32][33];
  const int k0 = blockIdx.y * 32, n0 = blockIdx.x * 32;
  const int r = threadIdx.x >> 3, c4 = (threadIdx.x & 7) * 4;
  const float4 v = *(const float4*)(src + (size_t)(k0 + r) * N + n0 + c4);
  t[r][c4] = v.x;
  t[r][c4 + 1] = v.y;
  t[r][c4 + 2] = v.z;
  t[r][c4 + 3] = v.w;
  __syncthreads();
  // write row n = r, k = k0 + c4 .. +3
  uint2 o;
  o.x = pack2(t[c4][r], t[c4 + 1][r]);
  o.y = pack2(t[c4 + 2][r], t[c4 + 3][r]);
  *(uint2*)(dst + (size_t)(n0 + r) * K + k0 + c4) = o;
}

// ---------------- K1: z = h @ red_w + red_b  (N x 16, fp32) ----------------
__global__ __launch_bounds__(256) void k_reduce(const float* __restrict__ h,
                                                const float* __restrict__ red_w,
                                                const float* __restrict__ red_b,
                                                float* __restrict__ z) {
  __shared__ alignas(16) u16 hs[16 * D_MODEL];  // bf16-rounded h tile, 32 KB
  const int tid = threadIdx.x;
  const int t0 = blockIdx.x * 16;

  const float4* src = (const float4*)(h + (size_t)t0 * D_MODEL);
  u32* dst = (u32*)hs;
#pragma unroll
  for (int it = 0; it < (16 * D_MODEL / 4) / 256; ++it) {
    const int idx = tid + it * 256;
    const float4 v = src[idx];
    dst[idx * 2 + 0] = pack2(v.x, v.y);
    dst[idx * 2 + 1] = pack2(v.z, v.w);
  }
  __syncthreads();

  const int m = tid >> 4, c = tid & 15;
  const u16* hrow = hs + m * D_MODEL;
  float acc = 0.f;
#pragma unroll 8
  for (int i = 0; i < D_MODEL; i += 2) {
    u32 hv = *(const u32*)(hrow + i);
    float h0 = __uint_as_float(hv << 16);
    float h1 = __uint_as_float(hv & 0xffff0000u);
    acc = fmaf(h0, red_w[i * R_DIM + c], acc);
    acc = fmaf(h1, red_w[(i + 1) * R_DIM + c], acc);
  }
  z[(size_t)(t0 + m) * R_DIM + c] = acc + red_b[c];
}

// ---- K2: plucker -> GEMM1 -> gelu, all 6 deltas -> A_cat (ct x 1536 bf16) --
__global__ __launch_bounds__(256) void k_plu(const float* __restrict__ z,
                                             const float* __restrict__ g1w,
                                             const float* __restrict__ g1b,
                                             u16* __restrict__ A, int t0g) {
  __shared__ alignas(16) float zs[16][17];
  __shared__ alignas(16) float zp[16][17];
  __shared__ alignas(16) float Ps[PLU][20];
  __shared__ alignas(16) float nrm[16][8];
  __shared__ float rno[16];

  const int tid = threadIdx.x;
  const int tl = blockIdx.x * 16;  // local token base (within chunk)
  const int tg = t0g + tl;         // global token base
  const int l0 = tg & (L_SEQ - 1);
  const int m = tid >> 4, c = tid & 15;

  zs[m][c] = z[(size_t)(tg + m) * R_DIM + c];
  const float b1 = g1b[tid];

#pragma unroll 1
  for (int dd = 0; dd < 6; ++dd) {
    const int delta = 1 << dd;
    __syncthreads();  // previous iter fully consumed Ps; zs ready at dd=0
    zp[m][c] = (l0 + m >= delta) ? z[(size_t)(tg + m - delta) * R_DIM + c] : 0.f;
    __syncthreads();
    for (int idx = tid; idx < PLU * 16; idx += 256) {
      const int k = idx >> 4, mm = idx & 15;
      int pi, pj;
      pair_from_k(k, pi, pj);
      Ps[k][mm] = zp[mm][pi] * zs[mm][pj] - zp[mm][pj] * zs[mm][pi];
    }
    __syncthreads();
    if (tid < 128) {
      const int mm = tid >> 3, pp = tid & 7;
      float s = 0.f;
      for (int k = pp; k < PLU; k += 8) {
        const float v = Ps[k][mm];
        s = fmaf(v, v, s);
      }
      nrm[mm][pp] = s;
    }
    __syncthreads();
    if (tid < 16) {
      float s = 0.f;
#pragma unroll
      for (int pp = 0; pp < 8; ++pp) s += nrm[tid][pp];
      rno[tid] = 1.0f / fmaxf(sqrtf(s), 1e-6f);
    }
    __syncthreads();
    float a1[16];
#pragma unroll
    for (int mm = 0; mm < 16; ++mm) a1[mm] = 0.f;
    for (int k = 0; k < PLU; ++k) {
      const float w = g1w[k * G_DIM + tid];
      const float4 p0 = *(const float4*)&Ps[k][0];
      const float4 p1 = *(const float4*)&Ps[k][4];
      const float4 p2 = *(const float4*)&Ps[k][8];
      const float4 p3 = *(const float4*)&Ps[k][12];
      const float pv[16] = {p0.x, p0.y, p0.z, p0.w, p1.x, p1.y, p1.z, p1.w,
                            p2.x, p2.y, p2.z, p2.w, p3.x, p3.y, p3.z, p3.w};
#pragma unroll
      for (int mm = 0; mm < 16; ++mm) a1[mm] = fmaf(pv[mm], w, a1[mm]);
    }
#pragma unroll
    for (int mm = 0; mm < 16; ++mm) {
      const float x = a1[mm] * rno[mm] + b1;
      const float ge = 0.5f * x * (1.0f + erff(x * 0.70710678118654752f));
      A[(size_t)(tl + mm) * K_CAT + dd * G_DIM + tid] =
          (l0 + mm >= delta) ? f2bf(ge) : (u16)0;
    }
  }
}

// --- K3: MFMA GEMM  g = (A_cat @ W2_stacked + cnt*b2)/cnt  (ct x 1024 bf16) -
__global__ __launch_bounds__(256) void k_gemm2(const u16* __restrict__ A,
                                               const u16* __restrict__ W2t,
                                               const float* __restrict__ g2b,
                                               u16* __restrict__ g, int t0g) {
  __shared__ alignas(16) short As[128][32];
  __shared__ alignas(16) short Bs[128][32];
  const int tid = threadIdx.x, lane = tid & 63, w = tid >> 6;
  const int wm = w >> 1, wn = w & 1;
  const int ml = blockIdx.y * 128;  // local row base
  const int n0 = blockIdx.x * 128;

  f32x4 acc[4][4];
#pragma unroll
  for (int a = 0; a < 4; ++a)
#pragma unroll
    for (int b = 0; b < 4; ++b) acc[a][b] = (f32x4)(0.f);

  const int srow = tid >> 1, sh = (tid & 1) * 16;
  const u16* Asrc = A + (size_t)(ml + srow) * K_CAT + sh;
  const u16* Bsrc = W2t + (size_t)(n0 + srow) * G_DIM + sh;
  const int kq = (lane >> 4) * 8, mr = lane & 15;

#pragma unroll 1
  for (int k0 = 0; k0 < K_CAT; k0 += 32) {
    __syncthreads();
    *(uint4*)&As[srow][sh] = *(const uint4*)(Asrc + k0);
    *(uint4*)&As[srow][sh + 8] = *(const uint4*)(Asrc + k0 + 8);
    const int kb = k0 & (G_DIM - 1);
    *(uint4*)&Bs[srow][sh] = *(const uint4*)(Bsrc + kb);
    *(uint4*)&Bs[srow][sh + 8] = *(const uint4*)(Bsrc + kb + 8);
    __syncthreads();
    short8 af[4], bf[4];
#pragma unroll
    for (int mi = 0; mi < 4; ++mi)
      af[mi] = *(const short8*)&As[wm * 64 + mi * 16 + mr][kq];
#pragma unroll
    for (int ni = 0; ni < 4; ++ni)
      bf[ni] = *(const short8*)&Bs[wn * 64 + ni * 16 + mr][kq];
#pragma unroll
    for (int mi = 0; mi < 4; ++mi)
#pragma unroll
      for (int ni = 0; ni < 4; ++ni)
        acc[mi][ni] = __builtin_amdgcn_mfma_f32_16x16x32_bf16(
            af[mi], bf[ni], acc[mi][ni], 0, 0, 0);
  }

  const int colb = n0 + wn * 64 + (lane & 15);
#pragma unroll
  for (int mi = 0; mi < 4; ++mi) {
#pragma unroll
    for (int r = 0; r < 4; ++r) {
      const int rowl = ml + wm * 64 + mi * 16 + (lane >> 4) * 4 + r;
      const int l = (t0g + rowl) & (L_SEQ - 1);
      const float cnt = (float)((l >= 1) + (l >= 2) + (l >= 4) + (l >= 8) +
                                (l >= 16) + (l >= 32));
      const float inv = 1.0f / fmaxf(cnt, 1.0f);
#pragma unroll
      for (int ni = 0; ni < 4; ++ni) {
        const int col = colb + ni * 16;
        const float v = (acc[mi][ni][r] + cnt * g2b[col]) * inv;
        g[(size_t)rowl * D_MODEL + col] = f2bf(v);
      }
    }
  }
}

// --- K4: MFMA GEMM gate: alpha=sigmoid([h,g]@gate_w+b); out=a*h+(1-a)*g ----
__global__ __launch_bounds__(256) void k_gate(const float* __restrict__ h,
                                              const u16* __restrict__ g,
                                              const u16* __restrict__ WtG,
                                              const float* __restrict__ gb,
                                              float* __restrict__ out,
                                              int t0g) {
  __shared__ alignas(16) short As[128][32];
  __shared__ alignas(16) short Bs[128][32];
  const int tid = threadIdx.x, lane = tid & 63, w = tid >> 6;
  const int wm = w >> 1, wn = w & 1;
  const int ml = blockIdx.y * 128;
  const int n0 = blockIdx.x * 128;

  f32x4 acc[4][4];
#pragma unroll
  for (int a = 0; a < 4; ++a)
#pragma unroll
    for (int b = 0; b < 4; ++b) acc[a][b] = (f32x4)(0.f);

  const int srow = tid >> 1, sh = (tid & 1) * 16;
  const float* hsrc = h + (size_t)(t0g + ml + srow) * D_MODEL + sh;
  const u16* gsrc = g + (size_t)(ml + srow) * D_MODEL + sh;
  const u16* Bsrc = WtG + (size_t)(n0 + srow) * K_GATE + sh;
  const int kq = (lane >> 4) * 8, mr = lane & 15;

#pragma unroll 1
  for (int k0 = 0; k0 < K_GATE; k0 += 32) {
    __syncthreads();
    if (k0 < D_MODEL) {  // A from h (fp32 -> bf16 on the fly)
      const float4 v0 = *(const float4*)(hsrc + k0);
      const float4 v1 = *(const float4*)(hsrc + k0 + 4);
      const float4 v2 = *(const float4*)(hsrc + k0 + 8);
      const float4 v3 = *(const float4*)(hsrc + k0 + 12);
      uint4 o0, o1;
      o0.x = pack2(v0.x, v0.y);
      o0.y = pack2(v0.z, v0.w);
      o0.z = pack2(v1.x, v1.y);
      o0.w = pack2(v1.z, v1.w);
      o1.x = pack2(v2.x, v2.y);
      o1.y = pack2(v2.z, v2.w);
      o1.z = pack2(v3.x, v3.y);
      o1.w = pack2(v3.z, v3.w);
      *(uint4*)&As[srow][sh] = o0;
      *(uint4*)&As[srow][sh + 8] = o1;
    } else {  // A from g (bf16)
      *(uint4*)&As[srow][sh] = *(const uint4*)(gsrc + (k0 - D_MODEL));
      *(uint4*)&As[srow][sh + 8] = *(const uint4*)(gsrc + (k0 - D_MODEL) + 8);
    }
    *(uint4*)&Bs[srow][sh] = *(const uint4*)(Bsrc + k0);
    *(uint4*)&Bs[srow][sh + 8] = *(const uint4*)(Bsrc + k0 + 8);
    __syncthreads();
    short8 af[4], bf[4];
#pragma unroll
    for (int mi = 0; mi < 4; ++mi)
      af[mi] = *(const short8*)&As[wm * 64 + mi * 16 + mr][kq];
#pragma unroll
    for (int ni = 0; ni < 4; ++ni)
      bf[ni] = *(const short8*)&Bs[wn * 64 + ni * 16 + mr][kq];
#pragma unroll
    for (int mi = 0; mi < 4; ++mi)
#pragma unroll
      for (int ni = 0; ni < 4; ++ni)
        acc[mi][ni] = __builtin_amdgcn_mfma_f32_16x16x32_bf16(
            af[mi], bf[ni], acc[mi][ni], 0, 0, 0);
  }

  const int colb = n0 + wn * 64 + (lane & 15);
#pragma unroll
  for (int mi = 0; mi < 4; ++mi) {
#pragma unroll
    for (int r = 0; r < 4; ++r) {
      const int rowl = ml + wm * 64 + mi * 16 + (lane >> 4) * 4 + r;
      const size_t rowg = (size_t)(t0g + rowl) * D_MODEL;
#pragma unroll
      for (int ni = 0; ni < 4; ++ni) {
        const int col = colb + ni * 16;
        const float x = acc[mi][ni][r] + gb[col];
        const float al = 1.0f / (1.0f + expf(-x));
        const float hv = h[rowg + col];
        const float gv = bf2f(g[(size_t)rowl * D_MODEL + col]);
        out[rowg + col] = fmaf(al, hv - gv, gv);
      }
    }
  }
}

// ---------------------------- launch ---------------------------------------
extern "C" void kernel_launch(void* const* d_in, const int* in_sizes, int n_in,
                              void* d_out, int out_size, void* d_ws,
                              size_t ws_size, hipStream_t stream) {
  const float* h = (const float*)d_in[0];
  const float* red_w = (const float*)d_in[1];
  const float* red_b = (const float*)d_in[2];
  const float* g1w = (const float*)d_in[3];
  const float* g1b = (const float*)d_in[4];
  const float* g2w = (const float*)d_in[5];
  const float* g2b = (const float*)d_in[6];
  const float* gate_w = (const float*)d_in[7];
  const float* gate_b = (const float*)d_in[8];
  float* out = (float*)d_out;

  // pick smallest chunk count whose ws footprint fits
  const size_t fixed = ((size_t)N_TOK * R_DIM * 4 + 255 & ~(size_t)255)  // z
                       + (1024 * (size_t)K_GATE * 2)                      // WtG
                       + (1024 * (size_t)G_DIM * 2) + 1024;               // W2t
  int nc = 1;
  for (; nc <= 8; nc *= 2) {
    const size_t ct = N_TOK / nc;
    const size_t need = fixed + ct * (size_t)K_CAT * 2 + ct * (size_t)D_MODEL * 2 + 4096;
    if (need <= ws_size) break;
  }
  if (nc > 8) nc = 8;  // best effort
  const int ct = N_TOK / nc;

  char* p = (char*)d_ws;
  float* z = (float*)p;
  p += ((size_t)N_TOK * R_DIM * 4 + 255) & ~(size_t)255;
  u16* WtG = (u16*)p;
  p += 1024 * (size_t)K_GATE * 2;
  u16* W2t = (u16*)p;
  p += 1024 * (size_t)G_DIM * 2;
  u16* Abuf = (u16*)p;
  p += (size_t)ct * K_CAT * 2;
  u16* gbuf = (u16*)p;

  // prepass: z, transposed bf16 weights
  k_reduce<<<dim3(N_TOK / 16), 256, 0, stream>>>(h, red_w, red_b, z);
  k_cvtT<<<dim3(1024 / 32, G_DIM / 32), 256, 0, stream>>>(g2w, W2t, G_DIM, 1024);
  k_cvtT<<<dim3(1024 / 32, K_GATE / 32), 256, 0, stream>>>(gate_w, WtG, K_GATE, 1024);

  for (int c = 0; c < nc; ++c) {
    const int t0g = c * ct;
    k_plu<<<dim3(ct / 16), 256, 0, stream>>>(z, g1w, g1b, Abuf, t0g);
    k_gemm2<<<dim3(8, ct / 128), 256, 0, stream>>>(Abuf, W2t, g2b, gbuf, t0g);
    k_gate<<<dim3(8, ct / 128), 256, 0, stream>>>(h, gbuf, WtG, gate_b, out, t0g);
  }
}

// Round 5
// 480.104 us; speedup vs baseline: 3.9489x; 1.1814x over previous
//
#include <hip/hip_runtime.h>
#include <hip/hip_bf16.h>
#include <math.h>

typedef unsigned short u16;
typedef unsigned int u32;
typedef __attribute__((ext_vector_type(8))) short short8;
typedef __attribute__((ext_vector_type(4))) float f32x4;

#define L_SEQ 4096
#define N_TOK 16384
#define D_MODEL 1024
#define R_DIM 16
#define PLU 120
#define G_DIM 256
#define K_CAT 1536  // 6 deltas * 256
#define K_GATE 2048

__device__ __forceinline__ u16 f2bf(float f) {
  u32 x = __float_as_uint(f);
  u32 lsb = (x >> 16) & 1u;
  x += 0x7fffu + lsb;
  return (u16)(x >> 16);
}
__device__ __forceinline__ float bf2f(u16 u) {
  return __uint_as_float(((u32)u) << 16);
}
__device__ __forceinline__ u32 pack2(float a, float b) {
  return (u32)f2bf(a) | ((u32)f2bf(b) << 16);
}

__device__ __forceinline__ void pair_from_k(int k, int& pi, int& pj) {
  int i = 0, kk = k, span = R_DIM - 1;
  while (kk >= span) { kk -= span; --span; ++i; }
  pi = i;
  pj = i + 1 + kk;
}

// ---- K_cvtT: fp32 [K x N] -> bf16 [N x Kp] transpose, zero-pad k in [K,Kp) -
__global__ __launch_bounds__(256) void k_cvtT(const float* __restrict__ src,
                                              u16* __restrict__ dst, int K,
                                              int Kp, int N) {
  __shared__ float t[32][33];
  const int k0 = blockIdx.y * 32, n0 = blockIdx.x * 32;
  const int r = threadIdx.x >> 3, c4 = (threadIdx.x & 7) * 4;
  float4 v = {0.f, 0.f, 0.f, 0.f};
  if (k0 + r < K) v = *(const float4*)(src + (size_t)(k0 + r) * N + n0 + c4);
  t[r][c4] = v.x;
  t[r][c4 + 1] = v.y;
  t[r][c4 + 2] = v.z;
  t[r][c4 + 3] = v.w;
  __syncthreads();
  uint2 o;
  o.x = pack2(t[c4][r], t[c4 + 1][r]);
  o.y = pack2(t[c4 + 2][r], t[c4 + 3][r]);
  *(uint2*)(dst + (size_t)(n0 + r) * Kp + k0 + c4) = o;
}

// -- K1: z = h @ red_w + red_b (N x 16 fp32); also emit h as bf16 (N x 1024) -
__global__ __launch_bounds__(256) void k_reduce(const float* __restrict__ h,
                                                const float* __restrict__ red_w,
                                                const float* __restrict__ red_b,
                                                float* __restrict__ z,
                                                u16* __restrict__ hb) {
  __shared__ alignas(16) u16 hs[16 * D_MODEL];  // 32 KB
  const int tid = threadIdx.x;
  const int t0 = blockIdx.x * 16;

  const float4* src = (const float4*)(h + (size_t)t0 * D_MODEL);
  u32* dst = (u32*)hs;
#pragma unroll
  for (int it = 0; it < (16 * D_MODEL / 4) / 256; ++it) {
    const int idx = tid + it * 256;
    const float4 v = src[idx];
    dst[idx * 2 + 0] = pack2(v.x, v.y);
    dst[idx * 2 + 1] = pack2(v.z, v.w);
  }
  __syncthreads();

  // write back bf16 h
  {
    const uint4* s4 = (const uint4*)hs;
    uint4* d4 = (uint4*)(hb + (size_t)t0 * D_MODEL);
#pragma unroll
    for (int it = 0; it < (16 * D_MODEL / 8) / 256; ++it)
      d4[tid + it * 256] = s4[tid + it * 256];
  }

  const int m = tid >> 4, c = tid & 15;
  const u16* hrow = hs + m * D_MODEL;
  float acc = 0.f;
#pragma unroll 8
  for (int i = 0; i < D_MODEL; i += 2) {
    u32 hv = *(const u32*)(hrow + i);
    float h0 = __uint_as_float(hv << 16);
    float h1 = __uint_as_float(hv & 0xffff0000u);
    acc = fmaf(h0, red_w[i * R_DIM + c], acc);
    acc = fmaf(h1, red_w[(i + 1) * R_DIM + c], acc);
  }
  z[(size_t)(t0 + m) * R_DIM + c] = acc + red_b[c];
}

// ---- K2 (MFMA): plucker -> GEMM1 -> gelu for all 6 deltas -> A_cat bf16 ----
__global__ __launch_bounds__(256) void k_plu(const float* __restrict__ z,
                                             const u16* __restrict__ W1t,
                                             const float* __restrict__ g1b,
                                             u16* __restrict__ A, int t0g) {
  __shared__ alignas(16) float zx[160][17];    // rows tg-32 .. tg+127
  __shared__ alignas(16) u16 W1s[128][136];    // [n][k], k padded 120->128
  __shared__ alignas(16) u16 Pb[128][136];     // [m][k] bf16, pad zeros
  __shared__ float prt[128][2];
  __shared__ float rno[128];
  __shared__ float b1s[128];
  __shared__ u32 pairs[PLU];

  const int tid = threadIdx.x, lane = tid & 63, w = tid >> 6;
  const int wm = w >> 1, wn = w & 1;
  const int n0 = blockIdx.x * 128;  // 0 or 128 of G_DIM
  const int tl = blockIdx.y * 128;  // local token base
  const int tg = t0g + tl;
  const int l0 = tg & (L_SEQ - 1);
  const int kq = (lane >> 4) * 8, mr = lane & 15;

  if (tid < PLU) {
    int pi, pj;
    pair_from_k(tid, pi, pj);
    pairs[tid] = (u32)pi | ((u32)pj << 8);
  }
  if (tid < 128) b1s[tid] = g1b[n0 + tid];
  for (int r = tid; r < 160 * 16; r += 256) {
    const int rr = r >> 4, c = r & 15;
    int t = tg - 32 + rr;
    if (t < 0) t = 0;
    zx[rr][c] = z[(size_t)t * R_DIM + c];
  }
  {
    const uint4* src = (const uint4*)(W1t + (size_t)n0 * 128);
    for (int i = tid; i < 128 * 16; i += 256) {
      const int r = i >> 4, c = i & 15;
      *(uint4*)&W1s[r][c * 8] = src[i];
    }
  }

  f32x4 acc[4][4];

#pragma unroll 1
  for (int dd = 0; dd < 6; ++dd) {
    const int delta = 1 << dd;
    __syncthreads();  // staging ready (dd=0); prior frag reads done (dd>0)
    {
      const int row = tid >> 1, half = tid & 1;
      const int kb = half * 60;
      const float* zc = zx[32 + row];
      const float* zpr = zx[32 + row - delta];
      float s = 0.f;
      for (int k = 0; k < 60; ++k) {
        const u32 pr = pairs[kb + k];
        const int pi = pr & 0xff, pj = pr >> 8;
        const float p = zpr[pi] * zc[pj] - zpr[pj] * zc[pi];
        s = fmaf(p, p, s);
        Pb[row][kb + k] = f2bf(p);
      }
      if (half) {  // zero-fill k = 120..127
        uint4 zz = {0u, 0u, 0u, 0u};
        *(uint4*)&Pb[row][120] = zz;
      }
      prt[row][half] = s;
    }
    __syncthreads();
    if (tid < 128) {
      const float s = prt[tid][0] + prt[tid][1];
      rno[tid] = 1.0f / fmaxf(sqrtf(s), 1e-6f);
    }
    __syncthreads();
#pragma unroll
    for (int a = 0; a < 4; ++a)
#pragma unroll
      for (int b = 0; b < 4; ++b) acc[a][b] = (f32x4)(0.f);
#pragma unroll
    for (int k0 = 0; k0 < 128; k0 += 32) {
      short8 af[4], bfr[4];
#pragma unroll
      for (int mi = 0; mi < 4; ++mi)
        af[mi] = *(const short8*)&Pb[wm * 64 + mi * 16 + mr][k0 + kq];
#pragma unroll
      for (int ni = 0; ni < 4; ++ni)
        bfr[ni] = *(const short8*)&W1s[wn * 64 + ni * 16 + mr][k0 + kq];
#pragma unroll
      for (int mi = 0; mi < 4; ++mi)
#pragma unroll
        for (int ni = 0; ni < 4; ++ni)
          acc[mi][ni] = __builtin_amdgcn_mfma_f32_16x16x32_bf16(
              af[mi], bfr[ni], acc[mi][ni], 0, 0, 0);
    }
#pragma unroll
    for (int mi = 0; mi < 4; ++mi) {
#pragma unroll
      for (int r = 0; r < 4; ++r) {
        const int rowl = wm * 64 + mi * 16 + (lane >> 4) * 4 + r;
        const bool ok = (l0 + rowl) >= delta;
        const float rn = rno[rowl];
#pragma unroll
        for (int ni = 0; ni < 4; ++ni) {
          const int colL = wn * 64 + ni * 16 + mr;
          const float x = acc[mi][ni][r] * rn + b1s[colL];
          const float ge = 0.5f * x * (1.0f + erff(x * 0.70710678118654752f));
          A[(size_t)(tl + rowl) * K_CAT + dd * G_DIM + n0 + colL] =
              ok ? f2bf(ge) : (u16)0;
        }
      }
    }
  }
}

// --- K3: MFMA GEMM  g = (A_cat @ W2_stacked + cnt*b2)/cnt  (ct x 1024 bf16) -
__global__ __launch_bounds__(256) void k_gemm2(const u16* __restrict__ A,
                                               const u16* __restrict__ W2t,
                                               const float* __restrict__ g2b,
                                               u16* __restrict__ g, int t0g) {
  __shared__ alignas(16) short As[128][32];
  __shared__ alignas(16) short Bs[128][32];
  const int tid = threadIdx.x, lane = tid & 63, w = tid >> 6;
  const int wm = w >> 1, wn = w & 1;
  const int ml = blockIdx.y * 128;
  const int n0 = blockIdx.x * 128;

  f32x4 acc[4][4];
#pragma unroll
  for (int a = 0; a < 4; ++a)
#pragma unroll
    for (int b = 0; b < 4; ++b) acc[a][b] = (f32x4)(0.f);

  const int srow = tid >> 1, sh = (tid & 1) * 16;
  const u16* Asrc = A + (size_t)(ml + srow) * K_CAT + sh;
  const u16* Bsrc = W2t + (size_t)(n0 + srow) * G_DIM + sh;
  const int kq = (lane >> 4) * 8, mr = lane & 15;

#pragma unroll 1
  for (int k0 = 0; k0 < K_CAT; k0 += 32) {
    __syncthreads();
    *(uint4*)&As[srow][sh] = *(const uint4*)(Asrc + k0);
    *(uint4*)&As[srow][sh + 8] = *(const uint4*)(Asrc + k0 + 8);
    const int kb = k0 & (G_DIM - 1);
    *(uint4*)&Bs[srow][sh] = *(const uint4*)(Bsrc + kb);
    *(uint4*)&Bs[srow][sh + 8] = *(const uint4*)(Bsrc + kb + 8);
    __syncthreads();
    short8 af[4], bfr[4];
#pragma unroll
    for (int mi = 0; mi < 4; ++mi)
      af[mi] = *(const short8*)&As[wm * 64 + mi * 16 + mr][kq];
#pragma unroll
    for (int ni = 0; ni < 4; ++ni)
      bfr[ni] = *(const short8*)&Bs[wn * 64 + ni * 16 + mr][kq];
#pragma unroll
    for (int mi = 0; mi < 4; ++mi)
#pragma unroll
      for (int ni = 0; ni < 4; ++ni)
        acc[mi][ni] = __builtin_amdgcn_mfma_f32_16x16x32_bf16(
            af[mi], bfr[ni], acc[mi][ni], 0, 0, 0);
  }

  const int colb = n0 + wn * 64 + (lane & 15);
#pragma unroll
  for (int mi = 0; mi < 4; ++mi) {
#pragma unroll
    for (int r = 0; r < 4; ++r) {
      const int rowl = ml + wm * 64 + mi * 16 + (lane >> 4) * 4 + r;
      const int l = (t0g + rowl) & (L_SEQ - 1);
      const float cnt = (float)((l >= 1) + (l >= 2) + (l >= 4) + (l >= 8) +
                                (l >= 16) + (l >= 32));
      const float inv = 1.0f / fmaxf(cnt, 1.0f);
#pragma unroll
      for (int ni = 0; ni < 4; ++ni) {
        const int col = colb + ni * 16;
        const float v = (acc[mi][ni][r] + cnt * g2b[col]) * inv;
        g[(size_t)rowl * D_MODEL + col] = f2bf(v);
      }
    }
  }
}

// --- K4: MFMA gate: alpha=sigmoid([hb,g]@gate_w+b); out = a*h + (1-a)*g -----
__global__ __launch_bounds__(256) void k_gate(const u16* __restrict__ hb,
                                              const u16* __restrict__ g,
                                              const u16* __restrict__ WtG,
                                              const float* __restrict__ gb,
                                              float* __restrict__ out,
                                              int t0g) {
  __shared__ alignas(16) short As[128][32];
  __shared__ alignas(16) short Bs[128][32];
  const int tid = threadIdx.x, lane = tid & 63, w = tid >> 6;
  const int wm = w >> 1, wn = w & 1;
  const int ml = blockIdx.y * 128;
  const int n0 = blockIdx.x * 128;

  f32x4 acc[4][4];
#pragma unroll
  for (int a = 0; a < 4; ++a)
#pragma unroll
    for (int b = 0; b < 4; ++b) acc[a][b] = (f32x4)(0.f);

  const int srow = tid >> 1, sh = (tid & 1) * 16;
  const u16* h0src = hb + (size_t)(t0g + ml + srow) * D_MODEL + sh;
  const u16* g0src = g + (size_t)(ml + srow) * D_MODEL + sh;
  const u16* Bsrc = WtG + (size_t)(n0 + srow) * K_GATE + sh;
  const int kq = (lane >> 4) * 8, mr = lane & 15;

#pragma unroll 1
  for (int k0 = 0; k0 < K_GATE; k0 += 32) {
    __syncthreads();
    const u16* s = (k0 < D_MODEL) ? (h0src + k0) : (g0src + (k0 - D_MODEL));
    *(uint4*)&As[srow][sh] = *(const uint4*)s;
    *(uint4*)&As[srow][sh + 8] = *(const uint4*)(s + 8);
    *(uint4*)&Bs[srow][sh] = *(const uint4*)(Bsrc + k0);
    *(uint4*)&Bs[srow][sh + 8] = *(const uint4*)(Bsrc + k0 + 8);
    __syncthreads();
    short8 af[4], bfr[4];
#pragma unroll
    for (int mi = 0; mi < 4; ++mi)
      af[mi] = *(const short8*)&As[wm * 64 + mi * 16 + mr][kq];
#pragma unroll
    for (int ni = 0; ni < 4; ++ni)
      bfr[ni] = *(const short8*)&Bs[wn * 64 + ni * 16 + mr][kq];
#pragma unroll
    for (int mi = 0; mi < 4; ++mi)
#pragma unroll
      for (int ni = 0; ni < 4; ++ni)
        acc[mi][ni] = __builtin_amdgcn_mfma_f32_16x16x32_bf16(
            af[mi], bfr[ni], acc[mi][ni], 0, 0, 0);
  }

  const int colb = n0 + wn * 64 + (lane & 15);
#pragma unroll
  for (int mi = 0; mi < 4; ++mi) {
#pragma unroll
    for (int r = 0; r < 4; ++r) {
      const int rowl = ml + wm * 64 + mi * 16 + (lane >> 4) * 4 + r;
      const size_t rowg = (size_t)(t0g + rowl) * D_MODEL;
#pragma unroll
      for (int ni = 0; ni < 4; ++ni) {
        const int col = colb + ni * 16;
        const float x = acc[mi][ni][r] + gb[col];
        const float al = 1.0f / (1.0f + expf(-x));
        const float hv = bf2f(hb[rowg + col]);
        const float gv = bf2f(g[(size_t)rowl * D_MODEL + col]);
        out[rowg + col] = fmaf(al, hv - gv, gv);
      }
    }
  }
}

// ---------------------------- launch ---------------------------------------
extern "C" void kernel_launch(void* const* d_in, const int* in_sizes, int n_in,
                              void* d_out, int out_size, void* d_ws,
                              size_t ws_size, hipStream_t stream) {
  const float* h = (const float*)d_in[0];
  const float* red_w = (const float*)d_in[1];
  const float* red_b = (const float*)d_in[2];
  const float* g1w = (const float*)d_in[3];
  const float* g1b = (const float*)d_in[4];
  const float* g2w = (const float*)d_in[5];
  const float* g2b = (const float*)d_in[6];
  const float* gate_w = (const float*)d_in[7];
  const float* gate_b = (const float*)d_in[8];
  float* out = (float*)d_out;

  const size_t sz_z = ((size_t)N_TOK * R_DIM * 4 + 255) & ~(size_t)255;
  const size_t sz_hb = (size_t)N_TOK * D_MODEL * 2;
  const size_t sz_WtG = (size_t)D_MODEL * K_GATE * 2;
  const size_t sz_W2t = (size_t)D_MODEL * G_DIM * 2;
  const size_t sz_W1t = (size_t)G_DIM * 128 * 2;
  const size_t fixed = sz_z + sz_hb + sz_WtG + sz_W2t + sz_W1t + 4096;

  int nc = 1;
  for (; nc <= 8; nc *= 2) {
    const size_t ct = N_TOK / nc;
    if (fixed + ct * (size_t)K_CAT * 2 + ct * (size_t)D_MODEL * 2 <= ws_size)
      break;
  }
  if (nc > 8) nc = 8;
  const int ct = N_TOK / nc;

  char* p = (char*)d_ws;
  float* z = (float*)p;
  p += sz_z;
  u16* hb = (u16*)p;
  p += sz_hb;
  u16* WtG = (u16*)p;
  p += sz_WtG;
  u16* W2t = (u16*)p;
  p += sz_W2t;
  u16* W1t = (u16*)p;
  p += sz_W1t;
  u16* Abuf = (u16*)p;
  p += (size_t)ct * K_CAT * 2;
  u16* gbuf = (u16*)p;

  k_reduce<<<dim3(N_TOK / 16), 256, 0, stream>>>(h, red_w, red_b, z, hb);
  k_cvtT<<<dim3(G_DIM / 32, 128 / 32), 256, 0, stream>>>(g1w, W1t, PLU, 128,
                                                         G_DIM);
  k_cvtT<<<dim3(D_MODEL / 32, G_DIM / 32), 256, 0, stream>>>(g2w, W2t, G_DIM,
                                                             G_DIM, D_MODEL);
  k_cvtT<<<dim3(D_MODEL / 32, K_GATE / 32), 256, 0, stream>>>(
      gate_w, WtG, K_GATE, K_GATE, D_MODEL);

  for (int c = 0; c < nc; ++c) {
    const int t0g = c * ct;
    k_plu<<<dim3(2, ct / 128), 256, 0, stream>>>(z, W1t, g1b, Abuf, t0g);
    k_gemm2<<<dim3(8, ct / 128), 256, 0, stream>>>(Abuf, W2t, g2b, gbuf, t0g);
    k_gate<<<dim3(8, ct / 128), 256, 0, stream>>>(hb, gbuf, WtG, gate_b, out,
                                                  t0g);
  }
}